// Round 1
// baseline (164.859 us; speedup 1.0000x reference)
//
#include <hip/hip_runtime.h>
#include <hip/hip_bf16.h>
#include <math.h>

#define NB 32768
#define DD 128
#define HH 512
#define EE 16
#define TM 64

typedef __attribute__((ext_vector_type(8))) short short8;
typedef __attribute__((ext_vector_type(4))) float f32x4;

__device__ __forceinline__ unsigned short f2bf(float f) {
  union { float f; unsigned u; } v; v.f = f;
  unsigned r = v.u + 0x7fffu + ((v.u >> 16) & 1u);
  return (unsigned short)(r >> 16);
}

// Abramowitz-Stegun 7.1.26 erf, |eps| <= 1.5e-7 (far below bf16 noise)
__device__ __forceinline__ float fast_erf(float z) {
  float a = fabsf(z);
  float t = 1.0f / (1.0f + 0.3275911f * a);
  float y = t * (0.254829592f + t * (-0.284496736f + t * (1.421413741f +
            t * (-1.453152027f + t * 1.061405429f))));
  float r = 1.0f - y * __expf(-a * a);
  return z < 0.0f ? -r : r;
}

// ---------------- weight transpose + bf16 cast ----------------
// w1 (E,D,H) fp32 -> w1T (E,H,D) bf16 ; w2 (E,H,D) fp32 -> w2T (E,D,H) bf16
__global__ __launch_bounds__(256) void transpose_kernel(
    const float* __restrict__ w1, const float* __restrict__ w2,
    unsigned short* __restrict__ w1T, unsigned short* __restrict__ w2T) {
  __shared__ float tile[32][33];
  int b = blockIdx.x;
  int tx = threadIdx.x & 31, ty = threadIdx.x >> 5;
  if (b < 1024) {
    int e = b >> 6, t = b & 63;
    int d0 = (t >> 4) * 32, h0 = (t & 15) * 32;
    const float* src = w1 + (size_t)e * DD * HH;
    #pragma unroll
    for (int j = 0; j < 4; ++j)
      tile[ty + j * 8][tx] = src[(size_t)(d0 + ty + j * 8) * HH + h0 + tx];
    __syncthreads();
    unsigned short* dst = w1T + (size_t)e * HH * DD;
    #pragma unroll
    for (int j = 0; j < 4; ++j)
      dst[(size_t)(h0 + ty + j * 8) * DD + d0 + tx] = f2bf(tile[tx][ty + j * 8]);
  } else {
    int bb = b - 1024;
    int e = bb >> 6, t = bb & 63;
    int h0 = (t >> 2) * 32, d0 = (t & 3) * 32;
    const float* src = w2 + (size_t)e * HH * DD;
    #pragma unroll
    for (int j = 0; j < 4; ++j)
      tile[ty + j * 8][tx] = src[(size_t)(h0 + ty + j * 8) * DD + d0 + tx];
    __syncthreads();
    unsigned short* dst = w2T + (size_t)e * DD * HH;
    #pragma unroll
    for (int j = 0; j < 4; ++j)
      dst[(size_t)(d0 + ty + j * 8) * HH + h0 + tx] = f2bf(tile[tx][ty + j * 8]);
  }
}

// ---------------- gating: fp64 logits + block-aggregated bucket scatter ----------------
__global__ __launch_bounds__(256) void gate_kernel(
    const float* __restrict__ x, const float* __restrict__ wg,
    const float* __restrict__ bg, int* __restrict__ counts,
    int* __restrict__ rows) {
  __shared__ float sx[64][132];
  __shared__ double swg[DD][EE];
  __shared__ int lcnt[EE];
  __shared__ int gbase[EE];
  __shared__ int lslot[64];
  __shared__ int lexp[64];

  int tid = threadIdx.x;
  int base = blockIdx.x * 64;

  if (tid < EE) lcnt[tid] = 0;
  for (int i = tid; i < DD * EE; i += 256) swg[i >> 4][i & 15] = (double)wg[i];
  {
    int r = tid >> 2, c0 = (tid & 3) * 32;
    const float4* src = (const float4*)(x + (size_t)(base + r) * DD + c0);
    #pragma unroll
    for (int i = 0; i < 8; ++i)
      *(float4*)&sx[r][c0 + i * 4] = src[i];
  }
  __syncthreads();

  int r = tid >> 2;
  int e0 = (tid & 3) * 4;
  double acc[4];
  #pragma unroll
  for (int j = 0; j < 4; ++j) acc[j] = (double)bg[e0 + j];

  #pragma unroll 4
  for (int d = 0; d < DD; ++d) {
    double xv = (double)sx[r][d];
    #pragma unroll
    for (int j = 0; j < 4; ++j)
      acc[j] += xv * swg[d][e0 + j];
  }

  int beste = 0; double bestv = acc[0];
  #pragma unroll
  for (int j = 1; j < 4; ++j)
    if (acc[j] > bestv) { bestv = acc[j]; beste = j; }
  int ge = e0 + beste;

  #pragma unroll
  for (int off = 1; off < 4; off <<= 1) {
    double ov = __shfl_xor(bestv, off);
    int oe = __shfl_xor(ge, off);
    if (ov > bestv || (ov == bestv && oe < ge)) { bestv = ov; ge = oe; }
  }

  if ((tid & 3) == 0) {
    lslot[r] = atomicAdd(&lcnt[ge], 1);
    lexp[r] = ge;
  }
  __syncthreads();
  if (tid < EE && lcnt[tid] > 0)
    gbase[tid] = atomicAdd(&counts[tid], lcnt[tid]);
  __syncthreads();
  if ((tid & 3) == 0) {
    int e2 = lexp[r];
    rows[e2 * NB + gbase[e2] + lslot[r]] = base + r;
  }
}

// ---------------- grouped expert GEMM: out[r] = gelu(x[r]@w1[e]) @ w2[e] ----------------
// v2: grid transposed (e = blockIdx.x) so useful blocks get DENSE linear ids
//     (old (512,16) grid aliased all useful blocks onto ~32 CU slots mod 256).
//     Weight staging is register-prefetched one chunk ahead (T14 async-stage):
//     global loads for chunk k+1 fly during chunk k's MFMA/gelu; only the
//     vmcnt-wait + ds_write sit between the two barriers.
//     Mid-chunk barrier removed: sX/sH rows are wave-private (wave wv touches
//     only rows [wv*16, wv*16+16)), same-wave LDS RAW is ordered by lgkmcnt.
__global__ __launch_bounds__(256) void moe_gemm(
    const float* __restrict__ x, const unsigned short* __restrict__ w1T,
    const unsigned short* __restrict__ w2T, const int* __restrict__ counts,
    const int* __restrict__ rows, float* __restrict__ out) {
  int e = blockIdx.x;
  int cnt = counts[e];
  int base = blockIdx.y * TM;
  if (base >= cnt) return;

  __shared__ unsigned short sX[TM][136];   // gathered x rows, bf16, [m][d]
  __shared__ unsigned short sW1[64][136];  // w1T chunk [h_local][d]
  __shared__ unsigned short sW2[DD][72];   // w2T chunk [d][h_local]
  __shared__ unsigned short sH[TM][72];    // hidden chunk [m][h_local] (wave-private rows)

  int tid = threadIdx.x;
  // stage gathered X rows (fp32 -> bf16); wave-private rows, no barrier needed for sX
  {
    int m = tid >> 2;
    int c0 = (tid & 3) * 32;
    int ridx = base + m; if (ridx >= cnt) ridx = cnt - 1;
    int grow = rows[e * NB + ridx];
    const float4* src = (const float4*)(x + (size_t)grow * DD + c0);
    #pragma unroll
    for (int i = 0; i < 8; ++i) {
      float4 v = src[i];
      ushort4 p;
      p.x = f2bf(v.x); p.y = f2bf(v.y); p.z = f2bf(v.z); p.w = f2bf(v.w);
      *(ushort4*)&sX[m][c0 + i * 4] = p;
    }
  }

  int wv = tid >> 6;
  int l  = tid & 63;
  int lm = l & 15;
  int q  = l >> 4;
  int k0 = q * 8;

  // ---- weight prefetch registers (one chunk ahead) ----
  uint4 pf1[4], pf2[4];
  const uint4* w1base = (const uint4*)(w1T + (size_t)e * HH * DD);  // chunk hc at uint4 offset hc*1024

  // prologue: load chunk 0 -> regs -> LDS, then issue chunk 1 loads
  #pragma unroll
  for (int i = 0; i < 4; ++i) pf1[i] = w1base[tid + i * 256];
  #pragma unroll
  for (int i = 0; i < 4; ++i) {
    int u = tid + i * 256, r2 = u >> 3, c2 = u & 7;
    pf2[i] = *(const uint4*)(w2T + ((size_t)e * DD + r2) * HH + c2 * 8);
  }
  #pragma unroll
  for (int i = 0; i < 4; ++i) {
    int u = tid + i * 256, r2 = u >> 4, c2 = u & 15;
    *(uint4*)&sW1[r2][c2 * 8] = pf1[i];
  }
  #pragma unroll
  for (int i = 0; i < 4; ++i) {
    int u = tid + i * 256, r2 = u >> 3, c2 = u & 7;
    *(uint4*)&sW2[r2][c2 * 8] = pf2[i];
  }
  #pragma unroll
  for (int i = 0; i < 4; ++i) pf1[i] = w1base[1024 + tid + i * 256];
  #pragma unroll
  for (int i = 0; i < 4; ++i) {
    int u = tid + i * 256, r2 = u >> 3, c2 = u & 7;
    pf2[i] = *(const uint4*)(w2T + ((size_t)e * DD + r2) * HH + 64 + c2 * 8);
  }
  __syncthreads();

  f32x4 acc2[8];
  #pragma unroll
  for (int n = 0; n < 8; ++n) acc2[n] = (f32x4){0.f, 0.f, 0.f, 0.f};

  for (int hc = 0; hc < 8; ++hc) {
    // GEMM1: hidden(16x64 per wave) = Xg(16x128) @ W1chunk(128x64)
    f32x4 acc1[4];
    #pragma unroll
    for (int n = 0; n < 4; ++n) acc1[n] = (f32x4){0.f, 0.f, 0.f, 0.f};
    #pragma unroll
    for (int ks = 0; ks < 4; ++ks) {
      int kk = ks * 32 + k0;
      short8 a = *(const short8*)&sX[wv * 16 + lm][kk];
      #pragma unroll
      for (int n = 0; n < 4; ++n) {
        short8 bfr = *(const short8*)&sW1[n * 16 + lm][kk];
        acc1[n] = __builtin_amdgcn_mfma_f32_16x16x32_bf16(a, bfr, acc1[n], 0, 0, 0);
      }
    }
    // gelu -> bf16 -> sH (wave-private rows; no barrier, lgkmcnt orders RAW)
    #pragma unroll
    for (int n = 0; n < 4; ++n) {
      #pragma unroll
      for (int r = 0; r < 4; ++r) {
        float v = acc1[n][r];
        float g = 0.5f * v * (1.0f + fast_erf(v * 0.70710678118654752f));
        sH[wv * 16 + q * 4 + r][n * 16 + lm] = f2bf(g);
      }
    }
    // GEMM2 partial: out(16x128 per wave) += H(16x64) @ W2chunk(64x128)
    #pragma unroll
    for (int ks = 0; ks < 2; ++ks) {
      int kk = ks * 32 + k0;
      short8 a = *(const short8*)&sH[wv * 16 + lm][kk];
      #pragma unroll
      for (int n = 0; n < 8; ++n) {
        short8 bfr = *(const short8*)&sW2[n * 16 + lm][kk];
        acc2[n] = __builtin_amdgcn_mfma_f32_16x16x32_bf16(a, bfr, acc2[n], 0, 0, 0);
      }
    }
    if (hc < 7) {
      __syncthreads();  // all waves done reading sW1/sW2 for chunk hc
      // write prefetched chunk hc+1 (vmcnt wait lands here, ~1 chunk of latency slack)
      #pragma unroll
      for (int i = 0; i < 4; ++i) {
        int u = tid + i * 256, r2 = u >> 4, c2 = u & 15;
        *(uint4*)&sW1[r2][c2 * 8] = pf1[i];
      }
      #pragma unroll
      for (int i = 0; i < 4; ++i) {
        int u = tid + i * 256, r2 = u >> 3, c2 = u & 7;
        *(uint4*)&sW2[r2][c2 * 8] = pf2[i];
      }
      if (hc < 6) {
        int h0n = (hc + 2) * 64;
        #pragma unroll
        for (int i = 0; i < 4; ++i) pf1[i] = w1base[(size_t)(hc + 2) * 1024 + tid + i * 256];
        #pragma unroll
        for (int i = 0; i < 4; ++i) {
          int u = tid + i * 256, r2 = u >> 3, c2 = u & 7;
          pf2[i] = *(const uint4*)(w2T + ((size_t)e * DD + r2) * HH + h0n + c2 * 8);
        }
      }
      __syncthreads();  // chunk hc+1 staged
    }
  }

  // epilogue: scatter rows (score == 1.0 for top-1 softmax)
  #pragma unroll
  for (int r = 0; r < 4; ++r) {
    int ml = wv * 16 + q * 4 + r;
    int ridx = base + ml;
    if (ridx < cnt) {
      int grow = rows[e * NB + ridx];
      float* op = out + (size_t)grow * DD + lm;
      #pragma unroll
      for (int n = 0; n < 8; ++n) op[n * 16] = acc2[n][r];
    }
  }
}

extern "C" void kernel_launch(void* const* d_in, const int* in_sizes, int n_in,
                              void* d_out, int out_size, void* d_ws, size_t ws_size,
                              hipStream_t stream) {
  const float* x  = (const float*)d_in[0];
  const float* w1 = (const float*)d_in[1];
  const float* w2 = (const float*)d_in[2];
  const float* wg = (const float*)d_in[3];
  const float* bg = (const float*)d_in[4];
  float* out = (float*)d_out;

  int* counts = (int*)d_ws;
  int* rows   = (int*)((char*)d_ws + 1024);
  unsigned short* w1T = (unsigned short*)((char*)d_ws + 1024 + (size_t)EE * NB * 4);
  unsigned short* w2T = w1T + (size_t)EE * HH * DD;

  hipMemsetAsync(d_ws, 0, 64, stream);
  hipLaunchKernelGGL(transpose_kernel, dim3(2048), dim3(256), 0, stream, w1, w2, w1T, w2T);
  hipLaunchKernelGGL(gate_kernel, dim3(NB / 64), dim3(256), 0, stream, x, wg, bg, counts, rows);
  hipLaunchKernelGGL(moe_gemm, dim3(EE, NB / TM), dim3(256), 0, stream, x, w1T, w2T, counts, rows, out);
}

// Round 2
// 135.621 us; speedup vs baseline: 1.2156x; 1.2156x over previous
//
#include <hip/hip_runtime.h>
#include <hip/hip_bf16.h>
#include <math.h>

#define NB 32768
#define DD 128
#define HH 512
#define EE 16
#define TM 64
#define HC 32
#define NCH (HH / HC)

typedef __attribute__((ext_vector_type(8))) short short8;
typedef __attribute__((ext_vector_type(4))) float f32x4;

__device__ __forceinline__ unsigned short f2bf(float f) {
  union { float f; unsigned u; } v; v.f = f;
  unsigned r = v.u + 0x7fffu + ((v.u >> 16) & 1u);
  return (unsigned short)(r >> 16);
}

// Abramowitz-Stegun 7.1.26 erf, |eps| <= 1.5e-7 (far below bf16 noise)
__device__ __forceinline__ float fast_erf(float z) {
  float a = fabsf(z);
  float t = 1.0f / (1.0f + 0.3275911f * a);
  float y = t * (0.254829592f + t * (-0.284496736f + t * (1.421413741f +
            t * (-1.453152027f + t * 1.061405429f))));
  float r = 1.0f - y * __expf(-a * a);
  return z < 0.0f ? -r : r;
}

// ---------------- fused prep: gate (blocks 0..511) + weight transpose (512..1023) ----------
// The two jobs are independent; fusing them into one launch overlaps gate's fp64 VALU with
// the transpose's memory traffic and removes one kernel-serialization gap.
__global__ __launch_bounds__(256) void prep_kernel(
    const float* __restrict__ x, const float* __restrict__ wg,
    const float* __restrict__ bg, const float* __restrict__ w1,
    const float* __restrict__ w2, int* __restrict__ counts,
    int* __restrict__ rows, unsigned short* __restrict__ w1T,
    unsigned short* __restrict__ w2T) {
  __shared__ __align__(16) char smem[50816];
  int tid = threadIdx.x;

  if (blockIdx.x >= 512) {
    // ---- 64x64 fp32 tile transpose -> bf16 ----
    // w1 (E,D,H) -> w1T (E,H,D): 16 tiles/expert (2 d x 8 h)
    // w2 (E,H,D) -> w2T (E,D,H): 16 tiles/expert (8 h x 2 d)
    float (*tile)[65] = (float (*)[65])smem;   // 65: scalar LDS ops, 2-way max
    int tp = blockIdx.x - 512;
    const float* src; unsigned short* dst; int S, Sd;
    if (tp < 256) {
      int e = tp >> 4, t2 = tp & 15;
      int d0 = (t2 >> 3) * 64, h0 = (t2 & 7) * 64;
      src = w1 + (size_t)e * DD * HH + (size_t)d0 * HH + h0; S = HH;
      dst = w1T + (size_t)e * HH * DD + (size_t)h0 * DD + d0; Sd = DD;
    } else {
      int t = tp - 256;
      int e = t >> 4, t2 = t & 15;
      int h0 = (t2 >> 1) * 64, d0 = (t2 & 1) * 64;
      src = w2 + (size_t)e * HH * DD + (size_t)h0 * DD + d0; S = DD;
      dst = w2T + (size_t)e * DD * HH + (size_t)d0 * HH + h0; Sd = HH;
    }
    #pragma unroll
    for (int i = 0; i < 4; ++i) {
      int u = tid + i * 256, r = u >> 4, c = (u & 15) * 4;
      float4 v = *(const float4*)(src + (size_t)r * S + c);
      tile[r][c + 0] = v.x; tile[r][c + 1] = v.y;
      tile[r][c + 2] = v.z; tile[r][c + 3] = v.w;
    }
    __syncthreads();
    #pragma unroll
    for (int i = 0; i < 4; ++i) {
      int u = tid + i * 256, tr = u >> 4, tc = (u & 15) * 4;
      ushort4 p;
      p.x = f2bf(tile[tc + 0][tr]); p.y = f2bf(tile[tc + 1][tr]);
      p.z = f2bf(tile[tc + 2][tr]); p.w = f2bf(tile[tc + 3][tr]);
      *(ushort4*)(dst + (size_t)tr * Sd + tc) = p;
    }
    return;
  }

  // ---- gating: fp64 logits + block-aggregated bucket scatter ----
  float  (*sx)[132] = (float (*)[132])smem;              // 33792 B
  double (*swg)[EE] = (double (*)[EE])(smem + 33792);    // 16384 B
  int* lcnt  = (int*)(smem + 50176);
  int* gbase = lcnt + EE;
  int* lslot = gbase + EE;
  int* lexp  = lslot + 64;

  int base = blockIdx.x * 64;
  if (tid < EE) lcnt[tid] = 0;
  for (int i = tid; i < DD * EE; i += 256) swg[i >> 4][i & 15] = (double)wg[i];
  {
    int r = tid >> 2, c0 = (tid & 3) * 32;
    const float4* src = (const float4*)(x + (size_t)(base + r) * DD + c0);
    #pragma unroll
    for (int i = 0; i < 8; ++i)
      *(float4*)&sx[r][c0 + i * 4] = src[i];
  }
  __syncthreads();

  int r = tid >> 2;
  int e0 = (tid & 3) * 4;
  double acc[4];
  #pragma unroll
  for (int j = 0; j < 4; ++j) acc[j] = (double)bg[e0 + j];

  #pragma unroll 4
  for (int d = 0; d < DD; ++d) {
    double xv = (double)sx[r][d];
    #pragma unroll
    for (int j = 0; j < 4; ++j)
      acc[j] += xv * swg[d][e0 + j];
  }

  int beste = 0; double bestv = acc[0];
  #pragma unroll
  for (int j = 1; j < 4; ++j)
    if (acc[j] > bestv) { bestv = acc[j]; beste = j; }
  int ge = e0 + beste;

  #pragma unroll
  for (int off = 1; off < 4; off <<= 1) {
    double ov = __shfl_xor(bestv, off);
    int oe = __shfl_xor(ge, off);
    if (ov > bestv || (ov == bestv && oe < ge)) { bestv = ov; ge = oe; }
  }

  if ((tid & 3) == 0) {
    lslot[r] = atomicAdd(&lcnt[ge], 1);
    lexp[r] = ge;
  }
  __syncthreads();
  if (tid < EE && lcnt[tid] > 0)
    gbase[tid] = atomicAdd(&counts[tid], lcnt[tid]);
  __syncthreads();
  if ((tid & 3) == 0) {
    int e2 = lexp[r];
    rows[e2 * NB + gbase[e2] + lslot[r]] = base + r;
  }
}

// ---------------- grouped expert GEMM: out[r] = gelu(x[r]@w1[e]) @ w2[e] ----------------
// v3: X A-fragments live in registers (sX deleted); weight chunks double-buffered with
//     ONE barrier per chunk; unpadded XOR-swizzled LDS (36.8 KB); grid (16,512) keeps each
//     expert's blocks on one XCD (id%8 == e%8) for L2 weight locality.
// Swizzle invariant (write == read): element (row, col) of a [R][C]-short tile lives at
//   byte = row*C*2 + ((slot ^ f(row)) * 16) + (col&7)*2, slot = col>>3
//   f(row) = row&7 for 16-slot rows (C=128), (row>>1)&3 for 4-slot rows (C=32).
__global__ __launch_bounds__(256) void moe_gemm(
    const float* __restrict__ x, const unsigned short* __restrict__ w1T,
    const unsigned short* __restrict__ w2T, const int* __restrict__ counts,
    const int* __restrict__ rows, float* __restrict__ out) {
  int e = blockIdx.x;
  int cnt = counts[e];
  int base = blockIdx.y * TM;
  if (base >= cnt) return;

  __shared__ unsigned short sW1[2][HC][DD];   // [h][d], swizzled
  __shared__ unsigned short sW2[2][DD][HC];   // [d][h], swizzled
  __shared__ unsigned short sH[TM][HC];       // [m][h], swizzled, wave-private rows

  int tid = threadIdx.x;
  int wv = tid >> 6, l = tid & 63;
  int lm = l & 15, q = l >> 4;

  // X A-fragments in registers: xa[ks] holds X[m=lm][k = ks*32 + q*8 + j]
  short8 xa[4];
  {
    int ridx = base + wv * 16 + lm; if (ridx >= cnt) ridx = cnt - 1;
    int grow = rows[e * NB + ridx];
    const float* xr = x + (size_t)grow * DD + q * 8;
    #pragma unroll
    for (int ks = 0; ks < 4; ++ks) {
      f32x4 v0 = *(const f32x4*)(xr + ks * 32);
      f32x4 v1 = *(const f32x4*)(xr + ks * 32 + 4);
      short8 a;
      a[0] = f2bf(v0[0]); a[1] = f2bf(v0[1]); a[2] = f2bf(v0[2]); a[3] = f2bf(v0[3]);
      a[4] = f2bf(v1[0]); a[5] = f2bf(v1[1]); a[6] = f2bf(v1[2]); a[7] = f2bf(v1[3]);
      xa[ks] = a;
    }
  }

  // staging geometry (per thread, 2 uint4 each for sW1/sW2 per chunk)
  int r1s = tid >> 4, s1s = tid & 15;                    // sW1: rows r1s, r1s+16
  int sl1 = (s1s ^ (r1s & 7)) * 8;                       // (r+16)&7 == r&7
  int r2s = tid >> 2, s2s = tid & 3;                     // sW2: rows r2s, r2s+64
  int sl2 = (s2s ^ ((r2s >> 1) & 3)) * 8;                // ((r+64)>>1)&3 == (r>>1)&3

  // prologue: stage chunk 0 into buffer 0
  {
    const unsigned short* w1c = w1T + (size_t)e * HH * DD;
    const unsigned short* w2c = w2T + (size_t)e * DD * HH;
    uint4 a0 = *(const uint4*)(w1c + (size_t)tid * 8);
    uint4 a1 = *(const uint4*)(w1c + (size_t)(tid + 256) * 8);
    uint4 b0 = *(const uint4*)(w2c + (size_t)r2s * HH + s2s * 8);
    uint4 b1 = *(const uint4*)(w2c + (size_t)(r2s + 64) * HH + s2s * 8);
    *(uint4*)&sW1[0][r1s][sl1]      = a0;
    *(uint4*)&sW1[0][r1s + 16][sl1] = a1;
    *(uint4*)&sW2[0][r2s][sl2]      = b0;
    *(uint4*)&sW2[0][r2s + 64][sl2] = b1;
  }
  __syncthreads();

  f32x4 acc2[8];
  #pragma unroll
  for (int n = 0; n < 8; ++n) acc2[n] = (f32x4){0.f, 0.f, 0.f, 0.f};

  for (int hc = 0; hc < NCH; ++hc) {
    int b = hc & 1;

    // issue next chunk's global loads early (regs); ds_write after compute -> latency hidden
    uint4 pa0, pa1, pb0, pb1;
    if (hc + 1 < NCH) {
      const unsigned short* w1c = w1T + ((size_t)e * HH + (size_t)(hc + 1) * HC) * DD;
      const unsigned short* w2c = w2T + (size_t)e * DD * HH + (size_t)(hc + 1) * HC;
      pa0 = *(const uint4*)(w1c + (size_t)tid * 8);
      pa1 = *(const uint4*)(w1c + (size_t)(tid + 256) * 8);
      pb0 = *(const uint4*)(w2c + (size_t)r2s * HH + s2s * 8);
      pb1 = *(const uint4*)(w2c + (size_t)(r2s + 64) * HH + s2s * 8);
    }

    // GEMM1: hidden(16x32 per wave) = X(16x128, regs) @ W1chunk(128x32)
    f32x4 acc1[2];
    #pragma unroll
    for (int n = 0; n < 2; ++n) acc1[n] = (f32x4){0.f, 0.f, 0.f, 0.f};
    #pragma unroll
    for (int ks = 0; ks < 4; ++ks) {
      #pragma unroll
      for (int n = 0; n < 2; ++n) {
        int row = n * 16 + lm;
        int sl = ((ks * 4 + q) ^ (row & 7)) * 8;
        short8 bfr = *(const short8*)&sW1[b][row][sl];
        acc1[n] = __builtin_amdgcn_mfma_f32_16x16x32_bf16(xa[ks], bfr, acc1[n], 0, 0, 0);
      }
    }
    // gelu -> bf16 -> sH (wave-private rows; same-wave lgkmcnt orders RAW)
    #pragma unroll
    for (int n = 0; n < 2; ++n) {
      #pragma unroll
      for (int rr = 0; rr < 4; ++rr) {
        float v = acc1[n][rr];
        float g = 0.5f * v * (1.0f + fast_erf(v * 0.70710678118654752f));
        int row = wv * 16 + q * 4 + rr;
        int col = n * 16 + lm;
        int sl = ((col >> 3) ^ ((row >> 1) & 3)) * 8;
        sH[row][sl + (col & 7)] = f2bf(g);
      }
    }
    // GEMM2: out(16x128 per wave) += H(16x32) @ W2chunk(32x128)
    {
      int rowA = wv * 16 + lm;
      int slA = (q ^ ((rowA >> 1) & 3)) * 8;
      short8 a = *(const short8*)&sH[rowA][slA];
      #pragma unroll
      for (int n = 0; n < 8; ++n) {
        int row = n * 16 + lm;
        int sl = (q ^ ((row >> 1) & 3)) * 8;
        short8 bfr = *(const short8*)&sW2[b][row][sl];
        acc2[n] = __builtin_amdgcn_mfma_f32_16x16x32_bf16(a, bfr, acc2[n], 0, 0, 0);
      }
    }

    // write prefetched chunk into the other buffer (loads landed during compute)
    if (hc + 1 < NCH) {
      *(uint4*)&sW1[b ^ 1][r1s][sl1]      = pa0;
      *(uint4*)&sW1[b ^ 1][r1s + 16][sl1] = pa1;
      *(uint4*)&sW2[b ^ 1][r2s][sl2]      = pb0;
      *(uint4*)&sW2[b ^ 1][r2s + 64][sl2] = pb1;
    }
    __syncthreads();
  }

  // epilogue: scatter rows (score == 1.0 for top-1 softmax)
  #pragma unroll
  for (int rr = 0; rr < 4; ++rr) {
    int ml = wv * 16 + q * 4 + rr;
    int ridx = base + ml;
    if (ridx < cnt) {
      int grow = rows[e * NB + ridx];
      float* op = out + (size_t)grow * DD + lm;
      #pragma unroll
      for (int n = 0; n < 8; ++n) op[n * 16] = acc2[n][rr];
    }
  }
}

extern "C" void kernel_launch(void* const* d_in, const int* in_sizes, int n_in,
                              void* d_out, int out_size, void* d_ws, size_t ws_size,
                              hipStream_t stream) {
  const float* x  = (const float*)d_in[0];
  const float* w1 = (const float*)d_in[1];
  const float* w2 = (const float*)d_in[2];
  const float* wg = (const float*)d_in[3];
  const float* bg = (const float*)d_in[4];
  float* out = (float*)d_out;

  // workspace: [0,64) counts ; [1024, +2MB) rows ; w1T bf16 2MB ; w2T bf16 2MB
  int* counts = (int*)d_ws;
  int* rows   = (int*)((char*)d_ws + 1024);
  unsigned short* w1T = (unsigned short*)((char*)d_ws + 1024 + (size_t)EE * NB * 4);
  unsigned short* w2T = w1T + (size_t)EE * HH * DD;

  hipMemsetAsync(d_ws, 0, 64, stream);
  hipLaunchKernelGGL(prep_kernel, dim3(1024), dim3(256), 0, stream,
                     x, wg, bg, w1, w2, counts, rows, w1T, w2T);
  hipLaunchKernelGGL(moe_gemm, dim3(EE, NB / TM), dim3(256), 0, stream,
                     x, w1T, w2T, counts, rows, out);
}